// Round 6
// baseline (656.889 us; speedup 1.0000x reference)
//
#include <hip/hip_runtime.h>
#include <math.h>

// (B,T,C)=(4,4096,1024), 16 heads x 64, window 256, rope base 1e4.
#define T_SEQ 4096
#define CDIM  1024
#define WIN   256

// log2(10000)/32 — inv_freq[pi] = 2^(-pi * ROPE_C)
#define ROPE_C 0.415241012f
// 0.125 * log2(e): softmax in exp2 domain
#define SCALE_LOG2E 0.1803368801f

typedef __attribute__((ext_vector_type(8))) short short8;
typedef __attribute__((ext_vector_type(4))) float float4v;

__device__ __forceinline__ unsigned int f2bf(float f) {
  unsigned int u = __float_as_uint(f);
  u += 0x7fffu + ((u >> 16) & 1u);
  return u >> 16;
}

// async global->LDS, 16B per lane. LDS dest must be linear (wave base + lane*16).
__device__ __forceinline__ void gload16(const unsigned short* g, unsigned short* l) {
  __builtin_amdgcn_global_load_lds(
      (__attribute__((address_space(1))) void*)g,
      (__attribute__((address_space(3))) void*)l, 16, 0, 0);
}

// ---------------------------------------------------------------------------
// RoPE table: tab[t*32+pi] = {cos(t*inv[pi]), sin(t*inv[pi])}, 4096x32, 1 MiB.
// ---------------------------------------------------------------------------
__global__ __launch_bounds__(256)
void rope_tab(float2* __restrict__ tab) {
  const int i = blockIdx.x * 256 + threadIdx.x;   // 0..131071
  const int tpos = i >> 5, pi = i & 31;
  const float ang = (float)tpos * exp2f(-(float)pi * ROPE_C);
  tab[i] = make_float2(cosf(ang), sinf(ang));
}

// ---------------------------------------------------------------------------
// Permuted bias: q/k cols de-interleaved within each 64-col head
// (even pair-components -> 0..31, odd -> 32..63). v cols identity.
// ---------------------------------------------------------------------------
__global__ __launch_bounds__(256)
void perm_bias(const float* __restrict__ b, float* __restrict__ pb) {
  const int n = blockIdx.x * 256 + threadIdx.x;   // 0..3071
  int np = n;
  if (n < 2 * CDIM) np = (n & ~63) | ((n & 1) * 32) | ((n & 63) >> 1);
  pb[np] = b[n];
}

// ---------------------------------------------------------------------------
// x fp32 -> bf16, 8 elems/thread.
// ---------------------------------------------------------------------------
__global__ __launch_bounds__(256)
void cvt_f32_bf16(const float* __restrict__ src, unsigned short* __restrict__ dst) {
  const long i = ((long)blockIdx.x * 256 + threadIdx.x) * 8;
  float4 u0 = *(const float4*)(src + i);
  float4 u1 = *(const float4*)(src + i + 4);
  uint4 pk;
  pk.x = f2bf(u0.x) | (f2bf(u0.y) << 16);
  pk.y = f2bf(u0.z) | (f2bf(u0.w) << 16);
  pk.z = f2bf(u1.x) | (f2bf(u1.y) << 16);
  pk.w = f2bf(u1.z) | (f2bf(u1.w) << 16);
  *(uint4*)(dst + i) = pk;
}

// ---------------------------------------------------------------------------
// W fp32 [K][N] row-major -> W^T bf16 [N][K] linear. permqk=1: de-interleave
// rope pairs within each head for cols<2048 (dot-products invariant since q
// and k share the permutation; makes rope lane-local in the GEMM epilogue).
// ---------------------------------------------------------------------------
__global__ __launch_bounds__(256)
void transpose_cvt(const float* __restrict__ W, unsigned short* __restrict__ dst,
                   int K, int N, int permqk) {
  __shared__ float tile[32][33];
  const int tid = threadIdx.x;
  const int ktile = blockIdx.y * 32, ntile = blockIdx.x * 32;
  const int kl = tid >> 3, nl4 = (tid & 7) * 4;
  float4 v = *(const float4*)&W[(size_t)(ktile + kl) * N + ntile + nl4];
  tile[nl4 + 0][kl] = v.x;
  tile[nl4 + 1][kl] = v.y;
  tile[nl4 + 2][kl] = v.z;
  tile[nl4 + 3][kl] = v.w;
  __syncthreads();
  const int nl = tid >> 3, kl4 = (tid & 7) * 4;
  uint2 pk;
  pk.x = f2bf(tile[nl][kl4 + 0]) | (f2bf(tile[nl][kl4 + 1]) << 16);
  pk.y = f2bf(tile[nl][kl4 + 2]) | (f2bf(tile[nl][kl4 + 3]) << 16);
  int n = ntile + nl;
  if (permqk && n < 2 * CDIM) n = (n & ~63) | ((n & 1) * 32) | ((n & 63) >> 1);
  long i = (long)n * K + ktile + kl4;
  *(uint2*)(dst + i) = pk;
}

// ---------------------------------------------------------------------------
// Pure-bf16 MFMA GEMM: C = A(bf16 [M][K]) @ Bt(bf16 [N][K])^T + bias.
// 128x128 block, 4 waves, 16x16x32 mfma, BK=32.
// R6: T3 minimum-2-phase pipeline — double-buffered LDS (4 statically
// distinct arrays so LLVM disambiguates ds_read(buf0) vs gload-write(buf1)),
// stage tile t+1 BEFORE computing tile t, single __syncthreads per tile
// AFTER compute (compiler's vmcnt(0)-before-barrier then drains loads whose
// latency was hidden under the compute phase). Removes the
// stage->drain->compute serialization that held MfmaUtil at 28%.
// VGPR capped via min-waves=5 (R3: 104 VGPR -> -40% cliff).
// mode=1: bf16 out, lane-local rope (permuted-pair layout). mode=0: fp32.
// ---------------------------------------------------------------------------
__global__ __launch_bounds__(256, 5)
void gemm_bf16(const unsigned short* __restrict__ A,
               const unsigned short* __restrict__ Bt,
               const float* __restrict__ bias,
               const float2* __restrict__ ropetab,
               void* __restrict__ Cp, int ldc, int K, int mode, int nbx) {
  __shared__ unsigned short As0[128 * 32];
  __shared__ unsigned short Bs0[128 * 32];
  __shared__ unsigned short As1[128 * 32];
  __shared__ unsigned short Bs1[128 * 32];
  const int t = threadIdx.x;
  // XCD-chunked bijective swizzle (nwg % 8 == 0 for both call sites)
  const int nwg = gridDim.x;
  const int cpx = nwg >> 3;
  const int wg = blockIdx.x;
  const int swz = (wg & 7) * cpx + (wg >> 3);
  const int row0 = (swz / nbx) * 128, col0 = (swz % nbx) * 128;
  const int lane = t & 63, wave = t >> 6;
  const int wm = (wave >> 1) * 64, wn = (wave & 1) * 64;
  const int l15 = lane & 15, quad = lane >> 4;

  // staging map: thread t covers LDS elems [t*8, t*8+8) (+2048 for pass 1)
  // -> tile row sr = t>>2 (+64), LDS chunk t&3. Source chunk = (t&3)^((sr>>1)&3).
  const int sr = t >> 2;
  const int sc = (t & 3) ^ ((sr >> 1) & 3);
  const unsigned short* a0 = A + (size_t)(row0 + sr) * K + sc * 8;
  const unsigned short* b0 = Bt + (size_t)(col0 + sr) * K + sc * 8;

  float4v acc[4][4];
#pragma unroll
  for (int i = 0; i < 4; ++i)
#pragma unroll
    for (int j = 0; j < 4; ++j) acc[i][j] = (float4v){0.f, 0.f, 0.f, 0.f};

  auto stage = [&](unsigned short* As_, unsigned short* Bs_, int k0) {
    gload16(a0 + k0, &As_[t * 8]);
    gload16(a0 + (size_t)64 * K + k0, &As_[t * 8 + 2048]);
    gload16(b0 + k0, &Bs_[t * 8]);
    gload16(b0 + (size_t)64 * K + k0, &Bs_[t * 8 + 2048]);
  };
  auto compute = [&](const unsigned short* As_, const unsigned short* Bs_) {
    short8 af[4], bfr[4];
#pragma unroll
    for (int mt = 0; mt < 4; ++mt) {
      const int r = wm + mt * 16 + l15;
      af[mt] = *(const short8*)&As_[r * 32 + ((quad ^ ((r >> 1) & 3)) * 8)];
    }
#pragma unroll
    for (int nt = 0; nt < 4; ++nt) {
      const int r = wn + nt * 16 + l15;
      bfr[nt] = *(const short8*)&Bs_[r * 32 + ((quad ^ ((r >> 1) & 3)) * 8)];
    }
#pragma unroll
    for (int mt = 0; mt < 4; ++mt)
#pragma unroll
      for (int nt = 0; nt < 4; ++nt)
        acc[mt][nt] = __builtin_amdgcn_mfma_f32_16x16x32_bf16(af[mt], bfr[nt],
                                                              acc[mt][nt], 0, 0, 0);
  };

  // ---- prologue: tile 0 into buf0 ----
  stage(As0, Bs0, 0);
  __syncthreads();
  // ---- main: 2 tiles per iteration, stage-ahead, one barrier per tile ----
  for (int k0 = 0; k0 < K - 64; k0 += 64) {
    stage(As1, Bs1, k0 + 32);
    compute(As0, Bs0);
    __syncthreads();
    stage(As0, Bs0, k0 + 64);
    compute(As1, Bs1);
    __syncthreads();
  }
  // ---- tail: tiles K/32-2, K/32-1 ----
  stage(As1, Bs1, K - 32);
  compute(As0, Bs0);
  __syncthreads();
  compute(As1, Bs1);

  if (mode) {
    unsigned short* co = (unsigned short*)Cp;
    if (col0 < 2 * CDIM) {
      // ---- q/k block: lane-local rope; row-outer store order ----
      float bb1[2], bb2[2];
#pragma unroll
      for (int ntp = 0; ntp < 2; ++ntp) {
        bb1[ntp] = bias[col0 + wn + ntp * 16 + l15];
        bb2[ntp] = bias[col0 + wn + ntp * 16 + l15 + 32];
      }
#pragma unroll
      for (int mt = 0; mt < 4; ++mt) {
#pragma unroll
        for (int r = 0; r < 4; ++r) {
          const int row = row0 + wm + mt * 16 + quad * 4 + r;
          const float2* tb = &ropetab[(size_t)(row & (T_SEQ - 1)) * 32];
          unsigned short* rp0 = co + (size_t)row * ldc + col0 + wn;
#pragma unroll
          for (int ntp = 0; ntp < 2; ++ntp) {
            const float2 cs = tb[ntp * 16 + l15];
            const float x1 = acc[mt][ntp][r] + bb1[ntp];
            const float x2 = acc[mt][ntp + 2][r] + bb2[ntp];
            const float y1 = x1 * cs.x - x2 * cs.y;
            const float y2 = x1 * cs.y + x2 * cs.x;
            const float y1p = __shfl_xor(y1, 1);
            const float y2p = __shfl_xor(y2, 1);
            if (!(l15 & 1)) {
              *(unsigned int*)(rp0 + ntp * 16 + l15) = f2bf(y1) | (f2bf(y1p) << 16);
              *(unsigned int*)(rp0 + ntp * 16 + l15 + 32) = f2bf(y2) | (f2bf(y2p) << 16);
            }
          }
        }
      }
    } else {
      // ---- v block: bias only; row-outer store order ----
      float bb[4];
#pragma unroll
      for (int nt = 0; nt < 4; ++nt) bb[nt] = bias[col0 + wn + nt * 16 + l15];
#pragma unroll
      for (int mt = 0; mt < 4; ++mt) {
#pragma unroll
        for (int r = 0; r < 4; ++r) {
          const int row = row0 + wm + mt * 16 + quad * 4 + r;
          unsigned short* rp0 = co + (size_t)row * ldc + col0 + wn;
#pragma unroll
          for (int nt = 0; nt < 4; ++nt) {
            const float v = acc[mt][nt][r] + bb[nt];
            const float vp = __shfl_xor(v, 1);
            if (!(l15 & 1))
              *(unsigned int*)(rp0 + nt * 16 + l15) = f2bf(v) | (f2bf(vp) << 16);
          }
        }
      }
    }
  } else {
    // ---- fp32 epilogue (output GEMM): row-outer, 256B contiguous per row ----
    float* co = (float*)Cp;
    float bb[4];
#pragma unroll
    for (int nt = 0; nt < 4; ++nt) bb[nt] = bias[col0 + wn + nt * 16 + l15];
#pragma unroll
    for (int mt = 0; mt < 4; ++mt) {
#pragma unroll
      for (int r = 0; r < 4; ++r) {
        const int row = row0 + wm + mt * 16 + quad * 4 + r;
        float* rp0 = co + (size_t)row * ldc + col0 + wn;
#pragma unroll
        for (int nt = 0; nt < 4; ++nt)
          rp0[nt * 16 + l15] = acc[mt][nt][r] + bb[nt];
      }
    }
  }
}

// ---------------------------------------------------------------------------
// MFMA flash attention on bf16 qkv (q/k in permuted head layout — QK^T
// invariant). R6: defer-max (T13) — skip accy rescale + max update when
// __all(mx <= m+8); P bounded by 2^8, exact online-softmax algebra.
// ---------------------------------------------------------------------------
__global__ __launch_bounds__(256, 2)
void attn_mfma(const unsigned short* __restrict__ qkv, unsigned short* __restrict__ Y) {
  __shared__ unsigned short Ks[128 * 64];   // [key][d], 16 KiB
  __shared__ unsigned short Vt[64 * 128];   // [d][key], 16 KiB
  __shared__ unsigned short Ps[4][64 * 32]; // per-wave P chunk, 16 KiB

  const int w = blockIdx.x, h = blockIdx.y, b = blockIdx.z;
  const int t = threadIdx.x;
  const int lane = t & 63, wv = t >> 6;
  const int l15 = lane & 15, quad = lane >> 4;
  const int t0 = w * WIN;
  const size_t base = ((size_t)b * T_SEQ + t0) * 3072;

  // ---- Q A-frags: direct bf16 16B loads ----
  short8 qf[4][2];
#pragma unroll
  for (int mt = 0; mt < 4; ++mt) {
    const unsigned short* qp = qkv + base + (size_t)(wv * 64 + mt * 16 + l15) * 3072 + h * 64;
#pragma unroll
    for (int ks = 0; ks < 2; ++ks)
      qf[mt][ks] = *(const short8*)(qp + ks * 32 + quad * 8);
  }

  float4v accy[4][4];
#pragma unroll
  for (int i = 0; i < 4; ++i)
#pragma unroll
    for (int j = 0; j < 4; ++j) accy[i][j] = (float4v){0.f, 0.f, 0.f, 0.f};
  float m_[4][4], l_[4][4];
#pragma unroll
  for (int i = 0; i < 4; ++i)
#pragma unroll
    for (int j = 0; j < 4; ++j) { m_[i][j] = -3.0e38f; l_[i][j] = 0.f; }

  for (int half = 0; half < 2; ++half) {
    if (half) __syncthreads();   // all waves done reading previous half
    // ---- stage K half via global_load_lds ----
    {
      const int kr = t >> 3, kc = t & 7;
      const unsigned short* kp = qkv + base + (size_t)(half * 128 + kr) * 3072 + 1024 +
                                 h * 64 + ((kc ^ (kr & 7)) * 8);
      unsigned short* lp = &Ks[t * 8];
#pragma unroll
      for (int p = 0; p < 4; ++p)
        gload16(kp + (size_t)p * 32 * 3072, lp + p * 2048);
    }
    // ---- stage V^T half ----
    {
      const int kpair = 2 * (t & 63);
      const int d0 = (t >> 6) * 16;
      const unsigned short* v0 = qkv + base + (size_t)(half * 128 + kpair) * 3072 + 2048 +
                                 h * 64 + d0;
      const unsigned short* v1 = v0 + 3072;
      short8 a0[2], a1[2];
#pragma unroll
      for (int j = 0; j < 2; ++j) {
        a0[j] = *(const short8*)(v0 + j * 8);
        a1[j] = *(const short8*)(v1 + j * 8);
      }
      const int c = kpair >> 3;
#pragma unroll
      for (int j = 0; j < 2; ++j)
#pragma unroll
        for (int e = 0; e < 8; ++e) {
          const int d = d0 + 8 * j + e;
          const unsigned int pk = (unsigned int)(unsigned short)a0[j][e] |
                                  ((unsigned int)(unsigned short)a1[j][e] << 16);
          *(unsigned int*)&Vt[d * 128 + ((c ^ (d & 7)) * 8) + (kpair & 7)] = pk;
        }
    }
    asm volatile("s_waitcnt vmcnt(0)" ::: "memory");
    __syncthreads();

    for (int kc = 0; kc < 4; ++kc) {   // 32-key chunks within half
      short8 kf[2][2];
#pragma unroll
      for (int nt = 0; nt < 2; ++nt)
#pragma unroll
        for (int ks = 0; ks < 2; ++ks) {
          const int r = kc * 32 + nt * 16 + l15;
          const int c = ks * 4 + quad;
          kf[nt][ks] = *(const short8*)&Ks[r * 64 + ((c ^ (l15 & 7)) * 8)];
        }
      float4v s_[4][2];
#pragma unroll
      for (int mt = 0; mt < 4; ++mt)
#pragma unroll
        for (int nt = 0; nt < 2; ++nt) {
          s_[mt][nt] = __builtin_amdgcn_mfma_f32_16x16x32_bf16(
              qf[mt][0], kf[nt][0], (float4v){0.f, 0.f, 0.f, 0.f}, 0, 0, 0);
          s_[mt][nt] = __builtin_amdgcn_mfma_f32_16x16x32_bf16(
              qf[mt][1], kf[nt][1], s_[mt][nt], 0, 0, 0);
        }
      // ---- online softmax (defer-max) + P write ----
#pragma unroll
      for (int mt = 0; mt < 4; ++mt) {
#pragma unroll
        for (int reg = 0; reg < 4; ++reg) {
          float s0 = s_[mt][0][reg] * SCALE_LOG2E;
          float s1 = s_[mt][1][reg] * SCALE_LOG2E;
          float mx = fmaxf(s0, s1);
          mx = fmaxf(mx, __shfl_xor(mx, 1));
          mx = fmaxf(mx, __shfl_xor(mx, 2));
          mx = fmaxf(mx, __shfl_xor(mx, 4));
          mx = fmaxf(mx, __shfl_xor(mx, 8));
          const float m_old = m_[mt][reg];
          float p0, p1;
          if (__all(mx <= m_old + 8.f)) {
            // deferred: keep old max, P bounded by 2^8
            p0 = exp2f(s0 - m_old);
            p1 = exp2f(s1 - m_old);
          } else {
            const float mn = fmaxf(m_old, mx);
            const float al = exp2f(m_old - mn);
            p0 = exp2f(s0 - mn);
            p1 = exp2f(s1 - mn);
            l_[mt][reg] *= al;
            m_[mt][reg] = mn;
#pragma unroll
            for (int dt = 0; dt < 4; ++dt) accy[mt][dt][reg] *= al;
          }
          float ps = p0 + p1;
          ps += __shfl_xor(ps, 1);
          ps += __shfl_xor(ps, 2);
          ps += __shfl_xor(ps, 4);
          ps += __shfl_xor(ps, 8);
          l_[mt][reg] += ps;
          const float q0 = __shfl_xor(p0, 1);
          const float q1 = __shfl_xor(p1, 1);
          const unsigned int w0 = f2bf(p0) | (f2bf(q0) << 16);
          const unsigned int w1 = f2bf(p1) | (f2bf(q1) << 16);
          if (!(l15 & 1)) {
            const int row = mt * 16 + quad * 4 + reg;
            const int ca = (0 + (l15 >> 3)) ^ (row & 3);
            const int cb = (2 + (l15 >> 3)) ^ (row & 3);
            *(unsigned int*)&Ps[wv][row * 32 + ca * 8 + (l15 & 7)] = w0;
            *(unsigned int*)&Ps[wv][row * 32 + cb * 8 + (l15 & 7)] = w1;
          }
        }
      }
      // ---- P A-frags + V^T B-frags, y += P @ V ----
      short8 pf[4], vf[4];
#pragma unroll
      for (int mt = 0; mt < 4; ++mt) {
        const int row = mt * 16 + l15;
        pf[mt] = *(const short8*)&Ps[wv][row * 32 + ((quad ^ (l15 & 3)) * 8)];
      }
#pragma unroll
      for (int dt = 0; dt < 4; ++dt) {
        const int d = dt * 16 + l15;
        const int c = kc * 4 + quad;
        vf[dt] = *(const short8*)&Vt[d * 128 + ((c ^ (d & 7)) * 8)];
      }
#pragma unroll
      for (int mt = 0; mt < 4; ++mt)
#pragma unroll
        for (int dt = 0; dt < 4; ++dt)
          accy[mt][dt] = __builtin_amdgcn_mfma_f32_16x16x32_bf16(pf[mt], vf[dt],
                                                                 accy[mt][dt], 0, 0, 0);
    }
  }

  // ---- epilogue: y/l -> compact bf16 Y [16384][1024], 4B packed stores ----
#pragma unroll
  for (int mt = 0; mt < 4; ++mt) {
#pragma unroll
    for (int reg = 0; reg < 4; ++reg) {
      const float rl = 1.f / l_[mt][reg];
      const int row = wv * 64 + mt * 16 + quad * 4 + reg;
      unsigned short* yp = Y + ((size_t)b * T_SEQ + t0 + row) * CDIM + h * 64;
#pragma unroll
      for (int dt = 0; dt < 4; ++dt) {
        const float y = accy[mt][dt][reg] * rl;
        const float ypart = __shfl_xor(y, 1);
        if (!(l15 & 1))
          *(unsigned int*)(yp + dt * 16 + l15) = f2bf(y) | (f2bf(ypart) << 16);
      }
    }
  }
}

// ---------------------------------------------------------------------------
// ws layout (bytes): [0,96M) qkv bf16 [16384][3072]; [96M,128M) x bf16;
// [128M,160M) y bf16; [160M,166M) W_inT bf16 (permuted); [166M,168M) W_outT;
// [168M,169M) rope table float2 [4096][32]; [169M,+12K) permuted bias.
// ---------------------------------------------------------------------------
extern "C" void kernel_launch(void* const* d_in, const int* in_sizes, int n_in,
                              void* d_out, int out_size, void* d_ws, size_t ws_size,
                              hipStream_t stream) {
  const float* x     = (const float*)d_in[0];
  const float* W_in  = (const float*)d_in[1];
  const float* b_in  = (const float*)d_in[2];
  const float* W_out = (const float*)d_in[3];
  const float* b_out = (const float*)d_in[4];
  float* out = (float*)d_out;
  char* ws = (char*)d_ws;
  unsigned short* qkvb  = (unsigned short*)ws;
  unsigned short* Abf   = (unsigned short*)(ws + (96u << 20));
  unsigned short* Ybf   = (unsigned short*)(ws + (128u << 20));
  unsigned short* WinT  = (unsigned short*)(ws + (160u << 20));
  unsigned short* WoutT = (unsigned short*)(ws + (166u << 20));
  float2* ropetabp      = (float2*)(ws + (168u << 20));
  float* pbias          = (float*)(ws + (169u << 20));

  rope_tab<<<512, 256, 0, stream>>>(ropetabp);
  perm_bias<<<12, 256, 0, stream>>>(b_in, pbias);
  cvt_f32_bf16<<<8192, 256, 0, stream>>>(x, Abf);
  transpose_cvt<<<dim3(3072 / 32, 1024 / 32), 256, 0, stream>>>(W_in, WinT, 1024, 3072, 1);
  transpose_cvt<<<dim3(1024 / 32, 1024 / 32), 256, 0, stream>>>(W_out, WoutT, 1024, 1024, 0);
  gemm_bf16<<<dim3(24 * 128), 256, 0, stream>>>(
      Abf, WinT, pbias, ropetabp, qkvb, 3 * CDIM, CDIM, 1, 24);
  attn_mfma<<<dim3(T_SEQ / WIN, 16, 4), 256, 0, stream>>>(qkvb, Ybf);
  gemm_bf16<<<dim3(8 * 128), 256, 0, stream>>>(
      Ybf, WoutT, b_out, nullptr, out, CDIM, CDIM, 0, 8);
}

// Round 7
// 590.200 us; speedup vs baseline: 1.1130x; 1.1130x over previous
//
#include <hip/hip_runtime.h>
#include <math.h>

// (B,T,C)=(4,4096,1024), 16 heads x 64, window 256, rope base 1e4.
#define T_SEQ 4096
#define CDIM  1024
#define WIN   256

// log2(10000)/32 — inv_freq[pi] = 2^(-pi * ROPE_C)
#define ROPE_C 0.415241012f
// 0.125 * log2(e): softmax in exp2 domain
#define SCALE_LOG2E 0.1803368801f

typedef __attribute__((ext_vector_type(8))) short short8;
typedef __attribute__((ext_vector_type(4))) float float4v;

__device__ __forceinline__ unsigned int f2bf(float f) {
  unsigned int u = __float_as_uint(f);
  u += 0x7fffu + ((u >> 16) & 1u);
  return u >> 16;
}

// async global->LDS, 16B per lane. LDS dest must be linear (wave base + lane*16).
__device__ __forceinline__ void gload16(const unsigned short* g, unsigned short* l) {
  __builtin_amdgcn_global_load_lds(
      (__attribute__((address_space(1))) void*)g,
      (__attribute__((address_space(3))) void*)l, 16, 0, 0);
}

// ---------------------------------------------------------------------------
// RoPE table: tab[t*32+pi] = {cos(t*inv[pi]), sin(t*inv[pi])}, 4096x32, 1 MiB.
// ---------------------------------------------------------------------------
__global__ __launch_bounds__(256)
void rope_tab(float2* __restrict__ tab) {
  const int i = blockIdx.x * 256 + threadIdx.x;   // 0..131071
  const int tpos = i >> 5, pi = i & 31;
  const float ang = (float)tpos * exp2f(-(float)pi * ROPE_C);
  tab[i] = make_float2(cosf(ang), sinf(ang));
}

// ---------------------------------------------------------------------------
// Permuted bias: q/k cols de-interleaved within each 64-col head
// (even pair-components -> 0..31, odd -> 32..63). v cols identity.
// ---------------------------------------------------------------------------
__global__ __launch_bounds__(256)
void perm_bias(const float* __restrict__ b, float* __restrict__ pb) {
  const int n = blockIdx.x * 256 + threadIdx.x;   // 0..3071
  int np = n;
  if (n < 2 * CDIM) np = (n & ~63) | ((n & 1) * 32) | ((n & 63) >> 1);
  pb[np] = b[n];
}

// ---------------------------------------------------------------------------
// x fp32 -> bf16, 8 elems/thread.
// ---------------------------------------------------------------------------
__global__ __launch_bounds__(256)
void cvt_f32_bf16(const float* __restrict__ src, unsigned short* __restrict__ dst) {
  const long i = ((long)blockIdx.x * 256 + threadIdx.x) * 8;
  float4 u0 = *(const float4*)(src + i);
  float4 u1 = *(const float4*)(src + i + 4);
  uint4 pk;
  pk.x = f2bf(u0.x) | (f2bf(u0.y) << 16);
  pk.y = f2bf(u0.z) | (f2bf(u0.w) << 16);
  pk.z = f2bf(u1.x) | (f2bf(u1.y) << 16);
  pk.w = f2bf(u1.z) | (f2bf(u1.w) << 16);
  *(uint4*)(dst + i) = pk;
}

// ---------------------------------------------------------------------------
// W fp32 [K][N] row-major -> W^T bf16 [N][K] linear. permqk=1: de-interleave
// rope pairs within each head for cols<2048 (dot-products invariant since q
// and k share the permutation; makes rope lane-local in the GEMM epilogue).
// ---------------------------------------------------------------------------
__global__ __launch_bounds__(256)
void transpose_cvt(const float* __restrict__ W, unsigned short* __restrict__ dst,
                   int K, int N, int permqk) {
  __shared__ float tile[32][33];
  const int tid = threadIdx.x;
  const int ktile = blockIdx.y * 32, ntile = blockIdx.x * 32;
  const int kl = tid >> 3, nl4 = (tid & 7) * 4;
  float4 v = *(const float4*)&W[(size_t)(ktile + kl) * N + ntile + nl4];
  tile[nl4 + 0][kl] = v.x;
  tile[nl4 + 1][kl] = v.y;
  tile[nl4 + 2][kl] = v.z;
  tile[nl4 + 3][kl] = v.w;
  __syncthreads();
  const int nl = tid >> 3, kl4 = (tid & 7) * 4;
  uint2 pk;
  pk.x = f2bf(tile[nl][kl4 + 0]) | (f2bf(tile[nl][kl4 + 1]) << 16);
  pk.y = f2bf(tile[nl][kl4 + 2]) | (f2bf(tile[nl][kl4 + 3]) << 16);
  int n = ntile + nl;
  if (permqk && n < 2 * CDIM) n = (n & ~63) | ((n & 1) * 32) | ((n & 63) >> 1);
  long i = (long)n * K + ktile + kl4;
  *(uint2*)(dst + i) = pk;
}

// ---------------------------------------------------------------------------
// Pure-bf16 MFMA GEMM: C = A(bf16 [M][K]) @ Bt(bf16 [N][K])^T + bias.
// 128x128 block, 4 waves, 16x16x32 mfma. R7: BK=64 on the PROVEN R5 serial
// 2-barrier loop (R6's stage-ahead dbuf regressed 2x: lambda pointers erased
// array identity -> compiler drained vmcnt(0) before every compute).
// BK=64 halves the barrier-drain count per tile (16 steps vs 32) and makes
// staging fetch whole 128-B lines. LDS 32 KiB = 2 x [128][64]; rows stride
// 128 B (exact bank wrap) so reads swizzle chunk^(row&7) across all 32
// banks; staging source pre-swizzled, LDS dest linear (rule #21).
// VGPR capped via min-waves=5 (R3: VGPR cliff lesson).
// mode=1: bf16 out, lane-local rope (permuted-pair layout). mode=0: fp32.
// ---------------------------------------------------------------------------
__global__ __launch_bounds__(256, 5)
void gemm_bf16(const unsigned short* __restrict__ A,
               const unsigned short* __restrict__ Bt,
               const float* __restrict__ bias,
               const float2* __restrict__ ropetab,
               void* __restrict__ Cp, int ldc, int K, int mode, int nbx) {
  __shared__ unsigned short As[128 * 64];   // 16 KiB
  __shared__ unsigned short Bs[128 * 64];   // 16 KiB
  const int t = threadIdx.x;
  // XCD-chunked bijective swizzle (nwg % 8 == 0 for both call sites)
  const int nwg = gridDim.x;
  const int cpx = nwg >> 3;
  const int wg = blockIdx.x;
  const int swz = (wg & 7) * cpx + (wg >> 3);
  const int row0 = (swz / nbx) * 128, col0 = (swz % nbx) * 128;
  const int lane = t & 63, wave = t >> 6;
  const int wm = (wave >> 1) * 64, wn = (wave & 1) * 64;
  const int l15 = lane & 15, quad = lane >> 4;

  // BK=64 staging map: pass p (0..3) covers rows p*32..p*32+31.
  // Thread t: local row sr2 = t>>3 (0..31), LDS chunk t&7 (8 x 16B per row).
  // LDS dest linear: p*2048 + t*8. Source chunk = (t&7) ^ (sr2&7)
  // (p*32 ≡ 0 mod 8, so row&7 == sr2&7 for all passes).
  const int sr2 = t >> 3;
  const int scx = ((t & 7) ^ (sr2 & 7)) * 8;
  const unsigned short* a0 = A + (size_t)(row0 + sr2) * K + scx;
  const unsigned short* b0 = Bt + (size_t)(col0 + sr2) * K + scx;

  float4v acc[4][4];
#pragma unroll
  for (int i = 0; i < 4; ++i)
#pragma unroll
    for (int j = 0; j < 4; ++j) acc[i][j] = (float4v){0.f, 0.f, 0.f, 0.f};

  for (int k0 = 0; k0 < K; k0 += 64) {
    __syncthreads();                      // all waves done reading prev tile
#pragma unroll
    for (int p = 0; p < 4; ++p) {
      gload16(a0 + (size_t)(32 * p) * K + k0, &As[p * 2048 + t * 8]);
      gload16(b0 + (size_t)(32 * p) * K + k0, &Bs[p * 2048 + t * 8]);
    }
    asm volatile("s_waitcnt vmcnt(0)" ::: "memory");
    __syncthreads();                      // tile ready for everyone

#pragma unroll
    for (int kk = 0; kk < 2; ++kk) {
      short8 af[4], bfr[4];
#pragma unroll
      for (int mt = 0; mt < 4; ++mt) {
        const int r = wm + mt * 16 + l15;
        af[mt] = *(const short8*)&As[r * 64 + (((kk * 4 + quad) ^ (r & 7)) * 8)];
      }
#pragma unroll
      for (int nt = 0; nt < 4; ++nt) {
        const int r = wn + nt * 16 + l15;
        bfr[nt] = *(const short8*)&Bs[r * 64 + (((kk * 4 + quad) ^ (r & 7)) * 8)];
      }
#pragma unroll
      for (int mt = 0; mt < 4; ++mt)
#pragma unroll
        for (int nt = 0; nt < 4; ++nt)
          acc[mt][nt] = __builtin_amdgcn_mfma_f32_16x16x32_bf16(af[mt], bfr[nt],
                                                                acc[mt][nt], 0, 0, 0);
    }
  }

  if (mode) {
    unsigned short* co = (unsigned short*)Cp;
    if (col0 < 2 * CDIM) {
      // ---- q/k block: lane-local rope; row-outer store order ----
      float bb1[2], bb2[2];
#pragma unroll
      for (int ntp = 0; ntp < 2; ++ntp) {
        bb1[ntp] = bias[col0 + wn + ntp * 16 + l15];
        bb2[ntp] = bias[col0 + wn + ntp * 16 + l15 + 32];
      }
#pragma unroll
      for (int mt = 0; mt < 4; ++mt) {
#pragma unroll
        for (int r = 0; r < 4; ++r) {
          const int row = row0 + wm + mt * 16 + quad * 4 + r;
          const float2* tb = &ropetab[(size_t)(row & (T_SEQ - 1)) * 32];
          unsigned short* rp0 = co + (size_t)row * ldc + col0 + wn;
#pragma unroll
          for (int ntp = 0; ntp < 2; ++ntp) {
            const float2 cs = tb[ntp * 16 + l15];
            const float x1 = acc[mt][ntp][r] + bb1[ntp];
            const float x2 = acc[mt][ntp + 2][r] + bb2[ntp];
            const float y1 = x1 * cs.x - x2 * cs.y;
            const float y2 = x1 * cs.y + x2 * cs.x;
            const float y1p = __shfl_xor(y1, 1);
            const float y2p = __shfl_xor(y2, 1);
            if (!(l15 & 1)) {
              *(unsigned int*)(rp0 + ntp * 16 + l15) = f2bf(y1) | (f2bf(y1p) << 16);
              *(unsigned int*)(rp0 + ntp * 16 + l15 + 32) = f2bf(y2) | (f2bf(y2p) << 16);
            }
          }
        }
      }
    } else {
      // ---- v block: bias only; row-outer store order ----
      float bb[4];
#pragma unroll
      for (int nt = 0; nt < 4; ++nt) bb[nt] = bias[col0 + wn + nt * 16 + l15];
#pragma unroll
      for (int mt = 0; mt < 4; ++mt) {
#pragma unroll
        for (int r = 0; r < 4; ++r) {
          const int row = row0 + wm + mt * 16 + quad * 4 + r;
          unsigned short* rp0 = co + (size_t)row * ldc + col0 + wn;
#pragma unroll
          for (int nt = 0; nt < 4; ++nt) {
            const float v = acc[mt][nt][r] + bb[nt];
            const float vp = __shfl_xor(v, 1);
            if (!(l15 & 1))
              *(unsigned int*)(rp0 + nt * 16 + l15) = f2bf(v) | (f2bf(vp) << 16);
          }
        }
      }
    }
  } else {
    // ---- fp32 epilogue (output GEMM): row-outer, 256B contiguous per row ----
    float* co = (float*)Cp;
    float bb[4];
#pragma unroll
    for (int nt = 0; nt < 4; ++nt) bb[nt] = bias[col0 + wn + nt * 16 + l15];
#pragma unroll
    for (int mt = 0; mt < 4; ++mt) {
#pragma unroll
      for (int r = 0; r < 4; ++r) {
        const int row = row0 + wm + mt * 16 + quad * 4 + r;
        float* rp0 = co + (size_t)row * ldc + col0 + wn;
#pragma unroll
        for (int nt = 0; nt < 4; ++nt)
          rp0[nt * 16 + l15] = acc[mt][nt][r] + bb[nt];
      }
    }
  }
}

// ---------------------------------------------------------------------------
// MFMA flash attention on bf16 qkv (q/k in permuted head layout — QK^T
// invariant). Defer-max (T13): skip accy rescale + max update when
// __all(mx <= m+8); P bounded by 2^8, exact online-softmax algebra.
// ---------------------------------------------------------------------------
__global__ __launch_bounds__(256, 2)
void attn_mfma(const unsigned short* __restrict__ qkv, unsigned short* __restrict__ Y) {
  __shared__ unsigned short Ks[128 * 64];   // [key][d], 16 KiB
  __shared__ unsigned short Vt[64 * 128];   // [d][key], 16 KiB
  __shared__ unsigned short Ps[4][64 * 32]; // per-wave P chunk, 16 KiB

  const int w = blockIdx.x, h = blockIdx.y, b = blockIdx.z;
  const int t = threadIdx.x;
  const int lane = t & 63, wv = t >> 6;
  const int l15 = lane & 15, quad = lane >> 4;
  const int t0 = w * WIN;
  const size_t base = ((size_t)b * T_SEQ + t0) * 3072;

  // ---- Q A-frags: direct bf16 16B loads ----
  short8 qf[4][2];
#pragma unroll
  for (int mt = 0; mt < 4; ++mt) {
    const unsigned short* qp = qkv + base + (size_t)(wv * 64 + mt * 16 + l15) * 3072 + h * 64;
#pragma unroll
    for (int ks = 0; ks < 2; ++ks)
      qf[mt][ks] = *(const short8*)(qp + ks * 32 + quad * 8);
  }

  float4v accy[4][4];
#pragma unroll
  for (int i = 0; i < 4; ++i)
#pragma unroll
    for (int j = 0; j < 4; ++j) accy[i][j] = (float4v){0.f, 0.f, 0.f, 0.f};
  float m_[4][4], l_[4][4];
#pragma unroll
  for (int i = 0; i < 4; ++i)
#pragma unroll
    for (int j = 0; j < 4; ++j) { m_[i][j] = -3.0e38f; l_[i][j] = 0.f; }

  for (int half = 0; half < 2; ++half) {
    if (half) __syncthreads();   // all waves done reading previous half
    // ---- stage K half via global_load_lds ----
    {
      const int kr = t >> 3, kc = t & 7;
      const unsigned short* kp = qkv + base + (size_t)(half * 128 + kr) * 3072 + 1024 +
                                 h * 64 + ((kc ^ (kr & 7)) * 8);
      unsigned short* lp = &Ks[t * 8];
#pragma unroll
      for (int p = 0; p < 4; ++p)
        gload16(kp + (size_t)p * 32 * 3072, lp + p * 2048);
    }
    // ---- stage V^T half ----
    {
      const int kpair = 2 * (t & 63);
      const int d0 = (t >> 6) * 16;
      const unsigned short* v0 = qkv + base + (size_t)(half * 128 + kpair) * 3072 + 2048 +
                                 h * 64 + d0;
      const unsigned short* v1 = v0 + 3072;
      short8 a0[2], a1[2];
#pragma unroll
      for (int j = 0; j < 2; ++j) {
        a0[j] = *(const short8*)(v0 + j * 8);
        a1[j] = *(const short8*)(v1 + j * 8);
      }
      const int c = kpair >> 3;
#pragma unroll
      for (int j = 0; j < 2; ++j)
#pragma unroll
        for (int e = 0; e < 8; ++e) {
          const int d = d0 + 8 * j + e;
          const unsigned int pk = (unsigned int)(unsigned short)a0[j][e] |
                                  ((unsigned int)(unsigned short)a1[j][e] << 16);
          *(unsigned int*)&Vt[d * 128 + ((c ^ (d & 7)) * 8) + (kpair & 7)] = pk;
        }
    }
    asm volatile("s_waitcnt vmcnt(0)" ::: "memory");
    __syncthreads();

    for (int kc = 0; kc < 4; ++kc) {   // 32-key chunks within half
      short8 kf[2][2];
#pragma unroll
      for (int nt = 0; nt < 2; ++nt)
#pragma unroll
        for (int ks = 0; ks < 2; ++ks) {
          const int r = kc * 32 + nt * 16 + l15;
          const int c = ks * 4 + quad;
          kf[nt][ks] = *(const short8*)&Ks[r * 64 + ((c ^ (l15 & 7)) * 8)];
        }
      float4v s_[4][2];
#pragma unroll
      for (int mt = 0; mt < 4; ++mt)
#pragma unroll
        for (int nt = 0; nt < 2; ++nt) {
          s_[mt][nt] = __builtin_amdgcn_mfma_f32_16x16x32_bf16(
              qf[mt][0], kf[nt][0], (float4v){0.f, 0.f, 0.f, 0.f}, 0, 0, 0);
          s_[mt][nt] = __builtin_amdgcn_mfma_f32_16x16x32_bf16(
              qf[mt][1], kf[nt][1], s_[mt][nt], 0, 0, 0);
        }
      // ---- online softmax (defer-max) + P write ----
#pragma unroll
      for (int mt = 0; mt < 4; ++mt) {
#pragma unroll
        for (int reg = 0; reg < 4; ++reg) {
          float s0 = s_[mt][0][reg] * SCALE_LOG2E;
          float s1 = s_[mt][1][reg] * SCALE_LOG2E;
          float mx = fmaxf(s0, s1);
          mx = fmaxf(mx, __shfl_xor(mx, 1));
          mx = fmaxf(mx, __shfl_xor(mx, 2));
          mx = fmaxf(mx, __shfl_xor(mx, 4));
          mx = fmaxf(mx, __shfl_xor(mx, 8));
          const float m_old = m_[mt][reg];
          float p0, p1;
          if (__all(mx <= m_old + 8.f)) {
            p0 = exp2f(s0 - m_old);
            p1 = exp2f(s1 - m_old);
          } else {
            const float mn = fmaxf(m_old, mx);
            const float al = exp2f(m_old - mn);
            p0 = exp2f(s0 - mn);
            p1 = exp2f(s1 - mn);
            l_[mt][reg] *= al;
            m_[mt][reg] = mn;
#pragma unroll
            for (int dt = 0; dt < 4; ++dt) accy[mt][dt][reg] *= al;
          }
          float ps = p0 + p1;
          ps += __shfl_xor(ps, 1);
          ps += __shfl_xor(ps, 2);
          ps += __shfl_xor(ps, 4);
          ps += __shfl_xor(ps, 8);
          l_[mt][reg] += ps;
          const float q0 = __shfl_xor(p0, 1);
          const float q1 = __shfl_xor(p1, 1);
          const unsigned int w0 = f2bf(p0) | (f2bf(q0) << 16);
          const unsigned int w1 = f2bf(p1) | (f2bf(q1) << 16);
          if (!(l15 & 1)) {
            const int row = mt * 16 + quad * 4 + reg;
            const int ca = (0 + (l15 >> 3)) ^ (row & 3);
            const int cb = (2 + (l15 >> 3)) ^ (row & 3);
            *(unsigned int*)&Ps[wv][row * 32 + ca * 8 + (l15 & 7)] = w0;
            *(unsigned int*)&Ps[wv][row * 32 + cb * 8 + (l15 & 7)] = w1;
          }
        }
      }
      // ---- P A-frags + V^T B-frags, y += P @ V ----
      short8 pf[4], vf[4];
#pragma unroll
      for (int mt = 0; mt < 4; ++mt) {
        const int row = mt * 16 + l15;
        pf[mt] = *(const short8*)&Ps[wv][row * 32 + ((quad ^ (l15 & 3)) * 8)];
      }
#pragma unroll
      for (int dt = 0; dt < 4; ++dt) {
        const int d = dt * 16 + l15;
        const int c = kc * 4 + quad;
        vf[dt] = *(const short8*)&Vt[d * 128 + ((c ^ (d & 7)) * 8)];
      }
#pragma unroll
      for (int mt = 0; mt < 4; ++mt)
#pragma unroll
        for (int dt = 0; dt < 4; ++dt)
          accy[mt][dt] = __builtin_amdgcn_mfma_f32_16x16x32_bf16(pf[mt], vf[dt],
                                                                 accy[mt][dt], 0, 0, 0);
    }
  }

  // ---- epilogue: y/l -> compact bf16 Y [16384][1024], 4B packed stores ----
#pragma unroll
  for (int mt = 0; mt < 4; ++mt) {
#pragma unroll
    for (int reg = 0; reg < 4; ++reg) {
      const float rl = 1.f / l_[mt][reg];
      const int row = wv * 64 + mt * 16 + quad * 4 + reg;
      unsigned short* yp = Y + ((size_t)b * T_SEQ + t0 + row) * CDIM + h * 64;
#pragma unroll
      for (int dt = 0; dt < 4; ++dt) {
        const float y = accy[mt][dt][reg] * rl;
        const float ypart = __shfl_xor(y, 1);
        if (!(l15 & 1))
          *(unsigned int*)(yp + dt * 16 + l15) = f2bf(y) | (f2bf(ypart) << 16);
      }
    }
  }
}

// ---------------------------------------------------------------------------
// ws layout (bytes): [0,96M) qkv bf16 [16384][3072]; [96M,128M) x bf16;
// [128M,160M) y bf16; [160M,166M) W_inT bf16 (permuted); [166M,168M) W_outT;
// [168M,169M) rope table float2 [4096][32]; [169M,+12K) permuted bias.
// ---------------------------------------------------------------------------
extern "C" void kernel_launch(void* const* d_in, const int* in_sizes, int n_in,
                              void* d_out, int out_size, void* d_ws, size_t ws_size,
                              hipStream_t stream) {
  const float* x     = (const float*)d_in[0];
  const float* W_in  = (const float*)d_in[1];
  const float* b_in  = (const float*)d_in[2];
  const float* W_out = (const float*)d_in[3];
  const float* b_out = (const float*)d_in[4];
  float* out = (float*)d_out;
  char* ws = (char*)d_ws;
  unsigned short* qkvb  = (unsigned short*)ws;
  unsigned short* Abf   = (unsigned short*)(ws + (96u << 20));
  unsigned short* Ybf   = (unsigned short*)(ws + (128u << 20));
  unsigned short* WinT  = (unsigned short*)(ws + (160u << 20));
  unsigned short* WoutT = (unsigned short*)(ws + (166u << 20));
  float2* ropetabp      = (float2*)(ws + (168u << 20));
  float* pbias          = (float*)(ws + (169u << 20));

  rope_tab<<<512, 256, 0, stream>>>(ropetabp);
  perm_bias<<<12, 256, 0, stream>>>(b_in, pbias);
  cvt_f32_bf16<<<8192, 256, 0, stream>>>(x, Abf);
  transpose_cvt<<<dim3(3072 / 32, 1024 / 32), 256, 0, stream>>>(W_in, WinT, 1024, 3072, 1);
  transpose_cvt<<<dim3(1024 / 32, 1024 / 32), 256, 0, stream>>>(W_out, WoutT, 1024, 1024, 0);
  gemm_bf16<<<dim3(24 * 128), 256, 0, stream>>>(
      Abf, WinT, pbias, ropetabp, qkvb, 3 * CDIM, CDIM, 1, 24);
  attn_mfma<<<dim3(T_SEQ / WIN, 16, 4), 256, 0, stream>>>(qkvb, Ybf);
  gemm_bf16<<<dim3(8 * 128), 256, 0, stream>>>(
      Ybf, WoutT, b_out, nullptr, out, CDIM, CDIM, 0, 8);
}

// Round 9
// 375.652 us; speedup vs baseline: 1.7487x; 1.5711x over previous
//
#include <hip/hip_runtime.h>
#include <math.h>

// (B,T,C)=(4,4096,1024), 16 heads x 64, window 256, rope base 1e4.
#define T_SEQ 4096
#define CDIM  1024
#define WIN   256

// log2(10000)/32 — inv_freq[pi] = 2^(-pi * ROPE_C)
#define ROPE_C 0.415241012f
// 0.125 * log2(e): softmax in exp2 domain
#define SCALE_LOG2E 0.1803368801f

typedef __attribute__((ext_vector_type(8))) short short8;
typedef __attribute__((ext_vector_type(4))) float float4v;

__device__ __forceinline__ unsigned int f2bf(float f) {
  unsigned int u = __float_as_uint(f);
  u += 0x7fffu + ((u >> 16) & 1u);
  return u >> 16;
}

// async global->LDS, 16B per lane. LDS dest must be linear (wave base + lane*16).
__device__ __forceinline__ void gload16(const unsigned short* g, unsigned short* l) {
  __builtin_amdgcn_global_load_lds(
      (__attribute__((address_space(1))) void*)g,
      (__attribute__((address_space(3))) void*)l, 16, 0, 0);
}

// ---------------------------------------------------------------------------
// RoPE table: tab[t*32+pi] = {cos(t*inv[pi]), sin(t*inv[pi])}, 4096x32, 1 MiB.
// ---------------------------------------------------------------------------
__global__ __launch_bounds__(256)
void rope_tab(float2* __restrict__ tab) {
  const int i = blockIdx.x * 256 + threadIdx.x;   // 0..131071
  const int tpos = i >> 5, pi = i & 31;
  const float ang = (float)tpos * exp2f(-(float)pi * ROPE_C);
  tab[i] = make_float2(cosf(ang), sinf(ang));
}

// ---------------------------------------------------------------------------
// Permuted bias: q/k cols de-interleaved within each 64-col head.
// ---------------------------------------------------------------------------
__global__ __launch_bounds__(256)
void perm_bias(const float* __restrict__ b, float* __restrict__ pb) {
  const int n = blockIdx.x * 256 + threadIdx.x;   // 0..3071
  int np = n;
  if (n < 2 * CDIM) np = (n & ~63) | ((n & 1) * 32) | ((n & 63) >> 1);
  pb[np] = b[n];
}

// ---------------------------------------------------------------------------
// x fp32 -> bf16, 8 elems/thread.
// ---------------------------------------------------------------------------
__global__ __launch_bounds__(256)
void cvt_f32_bf16(const float* __restrict__ src, unsigned short* __restrict__ dst) {
  const long i = ((long)blockIdx.x * 256 + threadIdx.x) * 8;
  float4 u0 = *(const float4*)(src + i);
  float4 u1 = *(const float4*)(src + i + 4);
  uint4 pk;
  pk.x = f2bf(u0.x) | (f2bf(u0.y) << 16);
  pk.y = f2bf(u0.z) | (f2bf(u0.w) << 16);
  pk.z = f2bf(u1.x) | (f2bf(u1.y) << 16);
  pk.w = f2bf(u1.z) | (f2bf(u1.w) << 16);
  *(uint4*)(dst + i) = pk;
}

// ---------------------------------------------------------------------------
// W fp32 [K][N] row-major -> W^T bf16 [N][K] linear. permqk=1: de-interleave
// rope pairs within each head for cols<2048.
// ---------------------------------------------------------------------------
__global__ __launch_bounds__(256)
void transpose_cvt(const float* __restrict__ W, unsigned short* __restrict__ dst,
                   int K, int N, int permqk) {
  __shared__ float tile[32][33];
  const int tid = threadIdx.x;
  const int ktile = blockIdx.y * 32, ntile = blockIdx.x * 32;
  const int kl = tid >> 3, nl4 = (tid & 7) * 4;
  float4 v = *(const float4*)&W[(size_t)(ktile + kl) * N + ntile + nl4];
  tile[nl4 + 0][kl] = v.x;
  tile[nl4 + 1][kl] = v.y;
  tile[nl4 + 2][kl] = v.z;
  tile[nl4 + 3][kl] = v.w;
  __syncthreads();
  const int nl = tid >> 3, kl4 = (tid & 7) * 4;
  uint2 pk;
  pk.x = f2bf(tile[nl][kl4 + 0]) | (f2bf(tile[nl][kl4 + 1]) << 16);
  pk.y = f2bf(tile[nl][kl4 + 2]) | (f2bf(tile[nl][kl4 + 3]) << 16);
  int n = ntile + nl;
  if (permqk && n < 2 * CDIM) n = (n & ~63) | ((n & 1) * 32) | ((n & 63) >> 1);
  long i = (long)n * K + ktile + kl4;
  *(uint2*)(dst + i) = pk;
}

// ---------------------------------------------------------------------------
// Pure-bf16 MFMA GEMM — EXACT R5 revert (162 µs proven). 128x128 block,
// 4 waves, 16x16x32 mfma, BK=32, LDS 16 KiB, serial 2-barrier loop.
// R6 (dbuf) and R7 (BK=64/32KiB) both regressed ~2x with FETCH/WRITE blowup
// (L2 thrash + partial-line write-back storm) — do not touch this loop.
// mode=1: bf16 out, lane-local rope (permuted-pair layout). mode=0: fp32.
// ---------------------------------------------------------------------------
__global__ __launch_bounds__(256, 5)
void gemm_bf16(const unsigned short* __restrict__ A,
               const unsigned short* __restrict__ Bt,
               const float* __restrict__ bias,
               const float2* __restrict__ ropetab,
               void* __restrict__ Cp, int ldc, int K, int mode, int nbx) {
  __shared__ unsigned short As[128 * 32];
  __shared__ unsigned short Bs[128 * 32];
  const int t = threadIdx.x;
  // XCD-chunked bijective swizzle (nwg % 8 == 0 for both call sites)
  const int nwg = gridDim.x;
  const int cpx = nwg >> 3;
  const int wg = blockIdx.x;
  const int swz = (wg & 7) * cpx + (wg >> 3);
  const int row0 = (swz / nbx) * 128, col0 = (swz % nbx) * 128;
  const int lane = t & 63, wave = t >> 6;
  const int wm = (wave >> 1) * 64, wn = (wave & 1) * 64;
  const int l15 = lane & 15, quad = lane >> 4;

  const int sr = t >> 2;
  const int sc = (t & 3) ^ ((sr >> 1) & 3);
  const unsigned short* a0 = A + (size_t)(row0 + sr) * K + sc * 8;
  const unsigned short* b0 = Bt + (size_t)(col0 + sr) * K + sc * 8;
  unsigned short* la = &As[t * 8];
  unsigned short* lb = &Bs[t * 8];

  float4v acc[4][4];
#pragma unroll
  for (int i = 0; i < 4; ++i)
#pragma unroll
    for (int j = 0; j < 4; ++j) acc[i][j] = (float4v){0.f, 0.f, 0.f, 0.f};

  for (int k0 = 0; k0 < K; k0 += 32) {
    __syncthreads();
    gload16(a0 + k0, la);
    gload16(a0 + (size_t)64 * K + k0, la + 2048);
    gload16(b0 + k0, lb);
    gload16(b0 + (size_t)64 * K + k0, lb + 2048);
    asm volatile("s_waitcnt vmcnt(0)" ::: "memory");
    __syncthreads();

    short8 af[4], bfr[4];
#pragma unroll
    for (int mt = 0; mt < 4; ++mt) {
      const int r = wm + mt * 16 + l15;
      af[mt] = *(const short8*)&As[r * 32 + ((quad ^ ((r >> 1) & 3)) * 8)];
    }
#pragma unroll
    for (int nt = 0; nt < 4; ++nt) {
      const int r = wn + nt * 16 + l15;
      bfr[nt] = *(const short8*)&Bs[r * 32 + ((quad ^ ((r >> 1) & 3)) * 8)];
    }
#pragma unroll
    for (int mt = 0; mt < 4; ++mt)
#pragma unroll
      for (int nt = 0; nt < 4; ++nt)
        acc[mt][nt] = __builtin_amdgcn_mfma_f32_16x16x32_bf16(af[mt], bfr[nt],
                                                              acc[mt][nt], 0, 0, 0);
  }

  if (mode) {
    unsigned short* co = (unsigned short*)Cp;
    if (col0 < 2 * CDIM) {
      float bb1[2], bb2[2];
#pragma unroll
      for (int ntp = 0; ntp < 2; ++ntp) {
        bb1[ntp] = bias[col0 + wn + ntp * 16 + l15];
        bb2[ntp] = bias[col0 + wn + ntp * 16 + l15 + 32];
      }
#pragma unroll
      for (int mt = 0; mt < 4; ++mt) {
#pragma unroll
        for (int r = 0; r < 4; ++r) {
          const int row = row0 + wm + mt * 16 + quad * 4 + r;
          const float2* tb = &ropetab[(size_t)(row & (T_SEQ - 1)) * 32];
          unsigned short* rp0 = co + (size_t)row * ldc + col0 + wn;
#pragma unroll
          for (int ntp = 0; ntp < 2; ++ntp) {
            const float2 cs = tb[ntp * 16 + l15];
            const float x1 = acc[mt][ntp][r] + bb1[ntp];
            const float x2 = acc[mt][ntp + 2][r] + bb2[ntp];
            const float y1 = x1 * cs.x - x2 * cs.y;
            const float y2 = x1 * cs.y + x2 * cs.x;
            const float y1p = __shfl_xor(y1, 1);
            const float y2p = __shfl_xor(y2, 1);
            if (!(l15 & 1)) {
              *(unsigned int*)(rp0 + ntp * 16 + l15) = f2bf(y1) | (f2bf(y1p) << 16);
              *(unsigned int*)(rp0 + ntp * 16 + l15 + 32) = f2bf(y2) | (f2bf(y2p) << 16);
            }
          }
        }
      }
    } else {
      float bb[4];
#pragma unroll
      for (int nt = 0; nt < 4; ++nt) bb[nt] = bias[col0 + wn + nt * 16 + l15];
#pragma unroll
      for (int mt = 0; mt < 4; ++mt) {
#pragma unroll
        for (int r = 0; r < 4; ++r) {
          const int row = row0 + wm + mt * 16 + quad * 4 + r;
          unsigned short* rp0 = co + (size_t)row * ldc + col0 + wn;
#pragma unroll
          for (int nt = 0; nt < 4; ++nt) {
            const float v = acc[mt][nt][r] + bb[nt];
            const float vp = __shfl_xor(v, 1);
            if (!(l15 & 1))
              *(unsigned int*)(rp0 + nt * 16 + l15) = f2bf(v) | (f2bf(vp) << 16);
          }
        }
      }
    }
  } else {
    float* co = (float*)Cp;
    float bb[4];
#pragma unroll
    for (int nt = 0; nt < 4; ++nt) bb[nt] = bias[col0 + wn + nt * 16 + l15];
#pragma unroll
    for (int mt = 0; mt < 4; ++mt) {
#pragma unroll
      for (int r = 0; r < 4; ++r) {
        const int row = row0 + wm + mt * 16 + quad * 4 + r;
        float* rp0 = co + (size_t)row * ldc + col0 + wn;
#pragma unroll
        for (int nt = 0; nt < 4; ++nt)
          rp0[nt * 16 + l15] = acc[mt][nt][r] + bb[nt];
      }
    }
  }
}

// ---------------------------------------------------------------------------
// MFMA flash attention, swapped QK^T (S^T = mfma(K,Q)): A/B frag layouts
// coincide for 16x16x32, so Q/K/V fragments are bit-identical to the old
// kernel; only operand order changes. C-layout: col=lane&15 -> QUERY,
// rows -> keys, so each lane owns 8 keys of its own query: row-max/sum =
// 7 local VALU + 2 shfls instead of 16 x 4-shfl chains. m/l: 4 scalars.
// P^T packs lane-locally into a stride-40-padded LDS row, read back as the
// PV B-frag; V^T frags serve as the PV A-operand (y^T accumulated).
// Defer-max kept. Epilogue: y^T -> LDS transpose (stride 72) -> 16B stores.
// ---------------------------------------------------------------------------
__global__ __launch_bounds__(256, 2)
void attn_mfma(const unsigned short* __restrict__ qkv, unsigned short* __restrict__ Y) {
  __shared__ unsigned short Ks[128 * 64];   // [key][d] swizzled, 16 KiB
  __shared__ unsigned short Vt[64 * 128];   // [d][key] swizzled, 16 KiB
  __shared__ unsigned short Ps[4][2048];    // per-wave scratch, 4 KiB each

  const int w = blockIdx.x, h = blockIdx.y, b = blockIdx.z;
  const int t = threadIdx.x;
  const int lane = t & 63, wv = t >> 6;
  const int l15 = lane & 15, quad = lane >> 4;
  const int t0 = w * WIN;
  const size_t base = ((size_t)b * T_SEQ + t0) * 3072;

  // ---- Q frags (same loads as before; used as B operand now) ----
  short8 qf[4][2];
#pragma unroll
  for (int qt = 0; qt < 4; ++qt) {
    const unsigned short* qp = qkv + base + (size_t)(wv * 64 + qt * 16 + l15) * 3072 + h * 64;
#pragma unroll
    for (int ks = 0; ks < 2; ++ks)
      qf[qt][ks] = *(const short8*)(qp + ks * 32 + quad * 8);
  }

  float4v accy[4][4];   // accy[dt][qt] = y^T frag: col=query(l15), row=d
#pragma unroll
  for (int i = 0; i < 4; ++i)
#pragma unroll
    for (int j = 0; j < 4; ++j) accy[i][j] = (float4v){0.f, 0.f, 0.f, 0.f};
  float m_[4], l_[4];   // per qt; query = wv*64 + qt*16 + l15
#pragma unroll
  for (int i = 0; i < 4; ++i) { m_[i] = -3.0e38f; l_[i] = 0.f; }

  for (int half = 0; half < 2; ++half) {
    if (half) __syncthreads();
    // ---- stage K half via global_load_lds (unchanged) ----
    {
      const int kr = t >> 3, kc = t & 7;
      const unsigned short* kp = qkv + base + (size_t)(half * 128 + kr) * 3072 + 1024 +
                                 h * 64 + ((kc ^ (kr & 7)) * 8);
      unsigned short* lp = &Ks[t * 8];
#pragma unroll
      for (int p = 0; p < 4; ++p)
        gload16(kp + (size_t)p * 32 * 3072, lp + p * 2048);
    }
    // ---- stage V^T half (unchanged) ----
    {
      const int kpair = 2 * (t & 63);
      const int d0 = (t >> 6) * 16;
      const unsigned short* v0 = qkv + base + (size_t)(half * 128 + kpair) * 3072 + 2048 +
                                 h * 64 + d0;
      const unsigned short* v1 = v0 + 3072;
      short8 a0[2], a1[2];
#pragma unroll
      for (int j = 0; j < 2; ++j) {
        a0[j] = *(const short8*)(v0 + j * 8);
        a1[j] = *(const short8*)(v1 + j * 8);
      }
      const int c = kpair >> 3;
#pragma unroll
      for (int j = 0; j < 2; ++j)
#pragma unroll
        for (int e = 0; e < 8; ++e) {
          const int d = d0 + 8 * j + e;
          const unsigned int pk = (unsigned int)(unsigned short)a0[j][e] |
                                  ((unsigned int)(unsigned short)a1[j][e] << 16);
          *(unsigned int*)&Vt[d * 128 + ((c ^ (d & 7)) * 8) + (kpair & 7)] = pk;
        }
    }
    asm volatile("s_waitcnt vmcnt(0)" ::: "memory");
    __syncthreads();

    for (int kc = 0; kc < 4; ++kc) {   // 32-key chunks within half
      // ---- K frags (A operand) + V^T frags (PV A operand), unchanged ----
      short8 kf[2][2];
#pragma unroll
      for (int kt = 0; kt < 2; ++kt)
#pragma unroll
        for (int ks = 0; ks < 2; ++ks) {
          const int r = kc * 32 + kt * 16 + l15;
          const int c = ks * 4 + quad;
          kf[kt][ks] = *(const short8*)&Ks[r * 64 + ((c ^ (l15 & 7)) * 8)];
        }
      short8 vf[4];
#pragma unroll
      for (int dt = 0; dt < 4; ++dt) {
        const int d = dt * 16 + l15;
        const int c = kc * 4 + quad;
        vf[dt] = *(const short8*)&Vt[d * 128 + ((c ^ (d & 7)) * 8)];
      }

#pragma unroll
      for (int qt = 0; qt < 4; ++qt) {
        // ---- S^T = mfma(K, Q): col=query(l15), rows=keys(quad*4+reg) ----
        float4v sT0 = __builtin_amdgcn_mfma_f32_16x16x32_bf16(
            kf[0][0], qf[qt][0], (float4v){0.f, 0.f, 0.f, 0.f}, 0, 0, 0);
        sT0 = __builtin_amdgcn_mfma_f32_16x16x32_bf16(kf[0][1], qf[qt][1], sT0, 0, 0, 0);
        float4v sT1 = __builtin_amdgcn_mfma_f32_16x16x32_bf16(
            kf[1][0], qf[qt][0], (float4v){0.f, 0.f, 0.f, 0.f}, 0, 0, 0);
        sT1 = __builtin_amdgcn_mfma_f32_16x16x32_bf16(kf[1][1], qf[qt][1], sT1, 0, 0, 0);

        float s0 = sT0[0] * SCALE_LOG2E, s1 = sT0[1] * SCALE_LOG2E;
        float s2 = sT0[2] * SCALE_LOG2E, s3 = sT0[3] * SCALE_LOG2E;
        float s4 = sT1[0] * SCALE_LOG2E, s5 = sT1[1] * SCALE_LOG2E;
        float s6 = sT1[2] * SCALE_LOG2E, s7 = sT1[3] * SCALE_LOG2E;

        float mx = fmaxf(fmaxf(fmaxf(s0, s1), fmaxf(s2, s3)),
                         fmaxf(fmaxf(s4, s5), fmaxf(s6, s7)));
        mx = fmaxf(mx, __shfl_xor(mx, 16));
        mx = fmaxf(mx, __shfl_xor(mx, 32));

        const float m_old = m_[qt];
        float p0, p1, p2, p3, p4, p5, p6, p7;
        if (__all(mx <= m_old + 8.f)) {
          p0 = exp2f(s0 - m_old); p1 = exp2f(s1 - m_old);
          p2 = exp2f(s2 - m_old); p3 = exp2f(s3 - m_old);
          p4 = exp2f(s4 - m_old); p5 = exp2f(s5 - m_old);
          p6 = exp2f(s6 - m_old); p7 = exp2f(s7 - m_old);
        } else {
          const float mn = fmaxf(m_old, mx);
          const float al = exp2f(m_old - mn);
          p0 = exp2f(s0 - mn); p1 = exp2f(s1 - mn);
          p2 = exp2f(s2 - mn); p3 = exp2f(s3 - mn);
          p4 = exp2f(s4 - mn); p5 = exp2f(s5 - mn);
          p6 = exp2f(s6 - mn); p7 = exp2f(s7 - mn);
          l_[qt] *= al;
          m_[qt] = mn;
#pragma unroll
          for (int dt = 0; dt < 4; ++dt) accy[dt][qt] *= al;
        }
        float ps = ((p0 + p1) + (p2 + p3)) + ((p4 + p5) + (p6 + p7));
        ps += __shfl_xor(ps, 16);
        ps += __shfl_xor(ps, 32);
        l_[qt] += ps;

        // ---- P^T -> LDS row (query l15, stride 40), lane-local pack ----
        unsigned short* pw = &Ps[wv][l15 * 40];
        *(unsigned int*)&pw[0 * 16 + quad * 4 + 0] = f2bf(p0) | (f2bf(p1) << 16);
        *(unsigned int*)&pw[0 * 16 + quad * 4 + 2] = f2bf(p2) | (f2bf(p3) << 16);
        *(unsigned int*)&pw[1 * 16 + quad * 4 + 0] = f2bf(p4) | (f2bf(p5) << 16);
        *(unsigned int*)&pw[1 * 16 + quad * 4 + 2] = f2bf(p6) | (f2bf(p7) << 16);
        // ---- PV B-frag: 8 keys quad*8..+8 of query l15 ----
        short8 pb = *(const short8*)&Ps[wv][l15 * 40 + quad * 8];
#pragma unroll
        for (int dt = 0; dt < 4; ++dt)
          accy[dt][qt] = __builtin_amdgcn_mfma_f32_16x16x32_bf16(vf[dt], pb,
                                                                accy[dt][qt], 0, 0, 0);
      }
    }
  }

  // ---- epilogue: y^T/l -> LDS transpose (stride 72) -> coalesced stores ----
#pragma unroll
  for (int qt = 0; qt < 4; ++qt) {
    const float rl = 1.f / l_[qt];
    unsigned short* ew = &Ps[wv][l15 * 72];
#pragma unroll
    for (int dt = 0; dt < 4; ++dt) {
      const float y0 = accy[dt][qt][0] * rl;
      const float y1 = accy[dt][qt][1] * rl;
      const float y2 = accy[dt][qt][2] * rl;
      const float y3 = accy[dt][qt][3] * rl;
      *(unsigned int*)&ew[dt * 16 + quad * 4 + 0] = f2bf(y0) | (f2bf(y1) << 16);
      *(unsigned int*)&ew[dt * 16 + quad * 4 + 2] = f2bf(y2) | (f2bf(y3) << 16);
    }
    // read row l15, d-range quad*16..+16; store 2x16B (wave fills whole lines)
    const int row = wv * 64 + qt * 16 + l15;
    unsigned short* yp = Y + ((size_t)b * T_SEQ + t0 + row) * CDIM + h * 64 + quad * 16;
    uint4 v0 = *(const uint4*)&Ps[wv][l15 * 72 + quad * 16];
    uint4 v1 = *(const uint4*)&Ps[wv][l15 * 72 + quad * 16 + 8];
    *(uint4*)yp = v0;
    *(uint4*)(yp + 8) = v1;
  }
}

// ---------------------------------------------------------------------------
// ws layout (bytes): [0,96M) qkv bf16 [16384][3072]; [96M,128M) x bf16;
// [128M,160M) y bf16; [160M,166M) W_inT bf16 (permuted); [166M,168M) W_outT;
// [168M,169M) rope table float2 [4096][32]; [169M,+12K) permuted bias.
// ---------------------------------------------------------------------------
extern "C" void kernel_launch(void* const* d_in, const int* in_sizes, int n_in,
                              void* d_out, int out_size, void* d_ws, size_t ws_size,
                              hipStream_t stream) {
  const float* x     = (const float*)d_in[0];
  const float* W_in  = (const float*)d_in[1];
  const float* b_in  = (const float*)d_in[2];
  const float* W_out = (const float*)d_in[3];
  const float* b_out = (const float*)d_in[4];
  float* out = (float*)d_out;
  char* ws = (char*)d_ws;
  unsigned short* qkvb  = (unsigned short*)ws;
  unsigned short* Abf   = (unsigned short*)(ws + (96u << 20));
  unsigned short* Ybf   = (unsigned short*)(ws + (128u << 20));
  unsigned short* WinT  = (unsigned short*)(ws + (160u << 20));
  unsigned short* WoutT = (unsigned short*)(ws + (166u << 20));
  float2* ropetabp      = (float2*)(ws + (168u << 20));
  float* pbias          = (float*)(ws + (169u << 20));

  rope_tab<<<512, 256, 0, stream>>>(ropetabp);
  perm_bias<<<12, 256, 0, stream>>>(b_in, pbias);
  cvt_f32_bf16<<<8192, 256, 0, stream>>>(x, Abf);
  transpose_cvt<<<dim3(3072 / 32, 1024 / 32), 256, 0, stream>>>(W_in, WinT, 1024, 3072, 1);
  transpose_cvt<<<dim3(1024 / 32, 1024 / 32), 256, 0, stream>>>(W_out, WoutT, 1024, 1024, 0);
  gemm_bf16<<<dim3(24 * 128), 256, 0, stream>>>(
      Abf, WinT, pbias, ropetabp, qkvb, 3 * CDIM, CDIM, 1, 24);
  attn_mfma<<<dim3(T_SEQ / WIN, 16, 4), 256, 0, stream>>>(qkvb, Ybf);
  gemm_bf16<<<dim3(8 * 128), 256, 0, stream>>>(
      Ybf, WoutT, b_out, nullptr, out, CDIM, CDIM, 0, 8);
}

// Round 10
// 364.907 us; speedup vs baseline: 1.8002x; 1.0294x over previous
//
#include <hip/hip_runtime.h>
#include <math.h>

// (B,T,C)=(4,4096,1024), 16 heads x 64, window 256, rope base 1e4.
#define T_SEQ 4096
#define CDIM  1024
#define WIN   256

// log2(10000)/32 — inv_freq[pi] = 2^(-pi * ROPE_C)
#define ROPE_C 0.415241012f
// 0.125 * log2(e): softmax in exp2 domain
#define SCALE_LOG2E 0.1803368801f

typedef __attribute__((ext_vector_type(8))) short short8;
typedef __attribute__((ext_vector_type(4))) float float4v;

__device__ __forceinline__ unsigned int f2bf(float f) {
  unsigned int u = __float_as_uint(f);
  u += 0x7fffu + ((u >> 16) & 1u);
  return u >> 16;
}

// async global->LDS, 16B per lane. LDS dest must be linear (wave base + lane*16).
__device__ __forceinline__ void gload16(const unsigned short* g, unsigned short* l) {
  __builtin_amdgcn_global_load_lds(
      (__attribute__((address_space(1))) void*)g,
      (__attribute__((address_space(3))) void*)l, 16, 0, 0);
}

// ---------------------------------------------------------------------------
// RoPE table: tab[t*32+pi] = {cos(t*inv[pi]), sin(t*inv[pi])}, 4096x32, 1 MiB.
// ---------------------------------------------------------------------------
__global__ __launch_bounds__(256)
void rope_tab(float2* __restrict__ tab) {
  const int i = blockIdx.x * 256 + threadIdx.x;   // 0..131071
  const int tpos = i >> 5, pi = i & 31;
  const float ang = (float)tpos * exp2f(-(float)pi * ROPE_C);
  tab[i] = make_float2(cosf(ang), sinf(ang));
}

// ---------------------------------------------------------------------------
// Permuted bias: q/k cols de-interleaved within each 64-col head.
// ---------------------------------------------------------------------------
__global__ __launch_bounds__(256)
void perm_bias(const float* __restrict__ b, float* __restrict__ pb) {
  const int n = blockIdx.x * 256 + threadIdx.x;   // 0..3071
  int np = n;
  if (n < 2 * CDIM) np = (n & ~63) | ((n & 1) * 32) | ((n & 63) >> 1);
  pb[np] = b[n];
}

// ---------------------------------------------------------------------------
// x fp32 -> bf16, 8 elems/thread.
// ---------------------------------------------------------------------------
__global__ __launch_bounds__(256)
void cvt_f32_bf16(const float* __restrict__ src, unsigned short* __restrict__ dst) {
  const long i = ((long)blockIdx.x * 256 + threadIdx.x) * 8;
  float4 u0 = *(const float4*)(src + i);
  float4 u1 = *(const float4*)(src + i + 4);
  uint4 pk;
  pk.x = f2bf(u0.x) | (f2bf(u0.y) << 16);
  pk.y = f2bf(u0.z) | (f2bf(u0.w) << 16);
  pk.z = f2bf(u1.x) | (f2bf(u1.y) << 16);
  pk.w = f2bf(u1.z) | (f2bf(u1.w) << 16);
  *(uint4*)(dst + i) = pk;
}

// ---------------------------------------------------------------------------
// W fp32 [K][N] row-major -> W^T bf16 [N][K] linear. permqk=1: de-interleave
// rope pairs within each head for cols<2048.
// ---------------------------------------------------------------------------
__global__ __launch_bounds__(256)
void transpose_cvt(const float* __restrict__ W, unsigned short* __restrict__ dst,
                   int K, int N, int permqk) {
  __shared__ float tile[32][33];
  const int tid = threadIdx.x;
  const int ktile = blockIdx.y * 32, ntile = blockIdx.x * 32;
  const int kl = tid >> 3, nl4 = (tid & 7) * 4;
  float4 v = *(const float4*)&W[(size_t)(ktile + kl) * N + ntile + nl4];
  tile[nl4 + 0][kl] = v.x;
  tile[nl4 + 1][kl] = v.y;
  tile[nl4 + 2][kl] = v.z;
  tile[nl4 + 3][kl] = v.w;
  __syncthreads();
  const int nl = tid >> 3, kl4 = (tid & 7) * 4;
  uint2 pk;
  pk.x = f2bf(tile[nl][kl4 + 0]) | (f2bf(tile[nl][kl4 + 1]) << 16);
  pk.y = f2bf(tile[nl][kl4 + 2]) | (f2bf(tile[nl][kl4 + 3]) << 16);
  int n = ntile + nl;
  if (permqk && n < 2 * CDIM) n = (n & ~63) | ((n & 1) * 32) | ((n & 63) >> 1);
  long i = (long)n * K + ktile + kl4;
  *(uint2*)(dst + i) = pk;
}

// ---------------------------------------------------------------------------
// Pure-bf16 MFMA GEMM — R5/R9 structure (proven), with the VGPR cap relaxed:
// min-waves 5 -> 3. m97 data: this exact loop hits 874 TF at VGPR=164 /
// 3 waves/SIMD; our 48-VGPR build delivered only 613 TF (compiler cannot
// software-pipeline ds_read vs MFMA with 48 regs). R3's "VGPR cliff" was
// confounded with its register-hungry epilogue (removed since R4).
// Loop structure untouched (R6/R7 lesson: do not touch the 2-barrier loop).
// mode=1: bf16 out, lane-local rope (permuted-pair layout). mode=0: fp32.
// ---------------------------------------------------------------------------
__global__ __launch_bounds__(256, 3)
void gemm_bf16(const unsigned short* __restrict__ A,
               const unsigned short* __restrict__ Bt,
               const float* __restrict__ bias,
               const float2* __restrict__ ropetab,
               void* __restrict__ Cp, int ldc, int K, int mode, int nbx) {
  __shared__ unsigned short As[128 * 32];
  __shared__ unsigned short Bs[128 * 32];
  const int t = threadIdx.x;
  // XCD-chunked bijective swizzle (nwg % 8 == 0 for both call sites)
  const int nwg = gridDim.x;
  const int cpx = nwg >> 3;
  const int wg = blockIdx.x;
  const int swz = (wg & 7) * cpx + (wg >> 3);
  const int row0 = (swz / nbx) * 128, col0 = (swz % nbx) * 128;
  const int lane = t & 63, wave = t >> 6;
  const int wm = (wave >> 1) * 64, wn = (wave & 1) * 64;
  const int l15 = lane & 15, quad = lane >> 4;

  const int sr = t >> 2;
  const int sc = (t & 3) ^ ((sr >> 1) & 3);
  const unsigned short* a0 = A + (size_t)(row0 + sr) * K + sc * 8;
  const unsigned short* b0 = Bt + (size_t)(col0 + sr) * K + sc * 8;
  unsigned short* la = &As[t * 8];
  unsigned short* lb = &Bs[t * 8];

  float4v acc[4][4];
#pragma unroll
  for (int i = 0; i < 4; ++i)
#pragma unroll
    for (int j = 0; j < 4; ++j) acc[i][j] = (float4v){0.f, 0.f, 0.f, 0.f};

  for (int k0 = 0; k0 < K; k0 += 32) {
    __syncthreads();
    gload16(a0 + k0, la);
    gload16(a0 + (size_t)64 * K + k0, la + 2048);
    gload16(b0 + k0, lb);
    gload16(b0 + (size_t)64 * K + k0, lb + 2048);
    asm volatile("s_waitcnt vmcnt(0)" ::: "memory");
    __syncthreads();

    short8 af[4], bfr[4];
#pragma unroll
    for (int mt = 0; mt < 4; ++mt) {
      const int r = wm + mt * 16 + l15;
      af[mt] = *(const short8*)&As[r * 32 + ((quad ^ ((r >> 1) & 3)) * 8)];
    }
#pragma unroll
    for (int nt = 0; nt < 4; ++nt) {
      const int r = wn + nt * 16 + l15;
      bfr[nt] = *(const short8*)&Bs[r * 32 + ((quad ^ ((r >> 1) & 3)) * 8)];
    }
#pragma unroll
    for (int mt = 0; mt < 4; ++mt)
#pragma unroll
      for (int nt = 0; nt < 4; ++nt)
        acc[mt][nt] = __builtin_amdgcn_mfma_f32_16x16x32_bf16(af[mt], bfr[nt],
                                                              acc[mt][nt], 0, 0, 0);
  }

  if (mode) {
    unsigned short* co = (unsigned short*)Cp;
    if (col0 < 2 * CDIM) {
      float bb1[2], bb2[2];
#pragma unroll
      for (int ntp = 0; ntp < 2; ++ntp) {
        bb1[ntp] = bias[col0 + wn + ntp * 16 + l15];
        bb2[ntp] = bias[col0 + wn + ntp * 16 + l15 + 32];
      }
#pragma unroll
      for (int mt = 0; mt < 4; ++mt) {
#pragma unroll
        for (int r = 0; r < 4; ++r) {
          const int row = row0 + wm + mt * 16 + quad * 4 + r;
          const float2* tb = &ropetab[(size_t)(row & (T_SEQ - 1)) * 32];
          unsigned short* rp0 = co + (size_t)row * ldc + col0 + wn;
#pragma unroll
          for (int ntp = 0; ntp < 2; ++ntp) {
            const float2 cs = tb[ntp * 16 + l15];
            const float x1 = acc[mt][ntp][r] + bb1[ntp];
            const float x2 = acc[mt][ntp + 2][r] + bb2[ntp];
            const float y1 = x1 * cs.x - x2 * cs.y;
            const float y2 = x1 * cs.y + x2 * cs.x;
            const float y1p = __shfl_xor(y1, 1);
            const float y2p = __shfl_xor(y2, 1);
            if (!(l15 & 1)) {
              *(unsigned int*)(rp0 + ntp * 16 + l15) = f2bf(y1) | (f2bf(y1p) << 16);
              *(unsigned int*)(rp0 + ntp * 16 + l15 + 32) = f2bf(y2) | (f2bf(y2p) << 16);
            }
          }
        }
      }
    } else {
      float bb[4];
#pragma unroll
      for (int nt = 0; nt < 4; ++nt) bb[nt] = bias[col0 + wn + nt * 16 + l15];
#pragma unroll
      for (int mt = 0; mt < 4; ++mt) {
#pragma unroll
        for (int r = 0; r < 4; ++r) {
          const int row = row0 + wm + mt * 16 + quad * 4 + r;
          unsigned short* rp0 = co + (size_t)row * ldc + col0 + wn;
#pragma unroll
          for (int nt = 0; nt < 4; ++nt) {
            const float v = acc[mt][nt][r] + bb[nt];
            const float vp = __shfl_xor(v, 1);
            if (!(l15 & 1))
              *(unsigned int*)(rp0 + nt * 16 + l15) = f2bf(v) | (f2bf(vp) << 16);
          }
        }
      }
    }
  } else {
    float* co = (float*)Cp;
    float bb[4];
#pragma unroll
    for (int nt = 0; nt < 4; ++nt) bb[nt] = bias[col0 + wn + nt * 16 + l15];
#pragma unroll
    for (int mt = 0; mt < 4; ++mt) {
#pragma unroll
      for (int r = 0; r < 4; ++r) {
        const int row = row0 + wm + mt * 16 + quad * 4 + r;
        float* rp0 = co + (size_t)row * ldc + col0 + wn;
#pragma unroll
        for (int nt = 0; nt < 4; ++nt)
          rp0[nt * 16 + l15] = acc[mt][nt][r] + bb[nt];
      }
    }
  }
}

// ---------------------------------------------------------------------------
// MFMA flash attention, swapped QK^T (R9, proven): S^T = mfma(K,Q); lane owns
// 8 keys of its own query -> row-max/sum = 7 local VALU + 2 shfls. P^T packs
// lane-locally into stride-40 LDS row, read back as PV B-frag; V^T frags are
// the PV A-operand (y^T accumulated). Defer-max kept.
// ---------------------------------------------------------------------------
__global__ __launch_bounds__(256, 2)
void attn_mfma(const unsigned short* __restrict__ qkv, unsigned short* __restrict__ Y) {
  __shared__ unsigned short Ks[128 * 64];   // [key][d] swizzled, 16 KiB
  __shared__ unsigned short Vt[64 * 128];   // [d][key] swizzled, 16 KiB
  __shared__ unsigned short Ps[4][2048];    // per-wave scratch, 4 KiB each

  const int w = blockIdx.x, h = blockIdx.y, b = blockIdx.z;
  const int t = threadIdx.x;
  const int lane = t & 63, wv = t >> 6;
  const int l15 = lane & 15, quad = lane >> 4;
  const int t0 = w * WIN;
  const size_t base = ((size_t)b * T_SEQ + t0) * 3072;

  // ---- Q frags (B operand) ----
  short8 qf[4][2];
#pragma unroll
  for (int qt = 0; qt < 4; ++qt) {
    const unsigned short* qp = qkv + base + (size_t)(wv * 64 + qt * 16 + l15) * 3072 + h * 64;
#pragma unroll
    for (int ks = 0; ks < 2; ++ks)
      qf[qt][ks] = *(const short8*)(qp + ks * 32 + quad * 8);
  }

  float4v accy[4][4];   // accy[dt][qt] = y^T frag: col=query(l15), row=d
#pragma unroll
  for (int i = 0; i < 4; ++i)
#pragma unroll
    for (int j = 0; j < 4; ++j) accy[i][j] = (float4v){0.f, 0.f, 0.f, 0.f};
  float m_[4], l_[4];   // per qt; query = wv*64 + qt*16 + l15
#pragma unroll
  for (int i = 0; i < 4; ++i) { m_[i] = -3.0e38f; l_[i] = 0.f; }

  for (int half = 0; half < 2; ++half) {
    if (half) __syncthreads();
    // ---- stage K half via global_load_lds ----
    {
      const int kr = t >> 3, kc = t & 7;
      const unsigned short* kp = qkv + base + (size_t)(half * 128 + kr) * 3072 + 1024 +
                                 h * 64 + ((kc ^ (kr & 7)) * 8);
      unsigned short* lp = &Ks[t * 8];
#pragma unroll
      for (int p = 0; p < 4; ++p)
        gload16(kp + (size_t)p * 32 * 3072, lp + p * 2048);
    }
    // ---- stage V^T half ----
    {
      const int kpair = 2 * (t & 63);
      const int d0 = (t >> 6) * 16;
      const unsigned short* v0 = qkv + base + (size_t)(half * 128 + kpair) * 3072 + 2048 +
                                 h * 64 + d0;
      const unsigned short* v1 = v0 + 3072;
      short8 a0[2], a1[2];
#pragma unroll
      for (int j = 0; j < 2; ++j) {
        a0[j] = *(const short8*)(v0 + j * 8);
        a1[j] = *(const short8*)(v1 + j * 8);
      }
      const int c = kpair >> 3;
#pragma unroll
      for (int j = 0; j < 2; ++j)
#pragma unroll
        for (int e = 0; e < 8; ++e) {
          const int d = d0 + 8 * j + e;
          const unsigned int pk = (unsigned int)(unsigned short)a0[j][e] |
                                  ((unsigned int)(unsigned short)a1[j][e] << 16);
          *(unsigned int*)&Vt[d * 128 + ((c ^ (d & 7)) * 8) + (kpair & 7)] = pk;
        }
    }
    asm volatile("s_waitcnt vmcnt(0)" ::: "memory");
    __syncthreads();

    for (int kc = 0; kc < 4; ++kc) {   // 32-key chunks within half
      short8 kf[2][2];
#pragma unroll
      for (int kt = 0; kt < 2; ++kt)
#pragma unroll
        for (int ks = 0; ks < 2; ++ks) {
          const int r = kc * 32 + kt * 16 + l15;
          const int c = ks * 4 + quad;
          kf[kt][ks] = *(const short8*)&Ks[r * 64 + ((c ^ (l15 & 7)) * 8)];
        }
      short8 vf[4];
#pragma unroll
      for (int dt = 0; dt < 4; ++dt) {
        const int d = dt * 16 + l15;
        const int c = kc * 4 + quad;
        vf[dt] = *(const short8*)&Vt[d * 128 + ((c ^ (d & 7)) * 8)];
      }

#pragma unroll
      for (int qt = 0; qt < 4; ++qt) {
        // ---- S^T = mfma(K, Q): col=query(l15), rows=keys(quad*4+reg) ----
        float4v sT0 = __builtin_amdgcn_mfma_f32_16x16x32_bf16(
            kf[0][0], qf[qt][0], (float4v){0.f, 0.f, 0.f, 0.f}, 0, 0, 0);
        sT0 = __builtin_amdgcn_mfma_f32_16x16x32_bf16(kf[0][1], qf[qt][1], sT0, 0, 0, 0);
        float4v sT1 = __builtin_amdgcn_mfma_f32_16x16x32_bf16(
            kf[1][0], qf[qt][0], (float4v){0.f, 0.f, 0.f, 0.f}, 0, 0, 0);
        sT1 = __builtin_amdgcn_mfma_f32_16x16x32_bf16(kf[1][1], qf[qt][1], sT1, 0, 0, 0);

        float s0 = sT0[0] * SCALE_LOG2E, s1 = sT0[1] * SCALE_LOG2E;
        float s2 = sT0[2] * SCALE_LOG2E, s3 = sT0[3] * SCALE_LOG2E;
        float s4 = sT1[0] * SCALE_LOG2E, s5 = sT1[1] * SCALE_LOG2E;
        float s6 = sT1[2] * SCALE_LOG2E, s7 = sT1[3] * SCALE_LOG2E;

        float mx = fmaxf(fmaxf(fmaxf(s0, s1), fmaxf(s2, s3)),
                         fmaxf(fmaxf(s4, s5), fmaxf(s6, s7)));
        mx = fmaxf(mx, __shfl_xor(mx, 16));
        mx = fmaxf(mx, __shfl_xor(mx, 32));

        const float m_old = m_[qt];
        float p0, p1, p2, p3, p4, p5, p6, p7;
        if (__all(mx <= m_old + 8.f)) {
          p0 = exp2f(s0 - m_old); p1 = exp2f(s1 - m_old);
          p2 = exp2f(s2 - m_old); p3 = exp2f(s3 - m_old);
          p4 = exp2f(s4 - m_old); p5 = exp2f(s5 - m_old);
          p6 = exp2f(s6 - m_old); p7 = exp2f(s7 - m_old);
        } else {
          const float mn = fmaxf(m_old, mx);
          const float al = exp2f(m_old - mn);
          p0 = exp2f(s0 - mn); p1 = exp2f(s1 - mn);
          p2 = exp2f(s2 - mn); p3 = exp2f(s3 - mn);
          p4 = exp2f(s4 - mn); p5 = exp2f(s5 - mn);
          p6 = exp2f(s6 - mn); p7 = exp2f(s7 - mn);
          l_[qt] *= al;
          m_[qt] = mn;
#pragma unroll
          for (int dt = 0; dt < 4; ++dt) accy[dt][qt] *= al;
        }
        float ps = ((p0 + p1) + (p2 + p3)) + ((p4 + p5) + (p6 + p7));
        ps += __shfl_xor(ps, 16);
        ps += __shfl_xor(ps, 32);
        l_[qt] += ps;

        // ---- P^T -> LDS row (query l15, stride 40), lane-local pack ----
        unsigned short* pw = &Ps[wv][l15 * 40];
        *(unsigned int*)&pw[0 * 16 + quad * 4 + 0] = f2bf(p0) | (f2bf(p1) << 16);
        *(unsigned int*)&pw[0 * 16 + quad * 4 + 2] = f2bf(p2) | (f2bf(p3) << 16);
        *(unsigned int*)&pw[1 * 16 + quad * 4 + 0] = f2bf(p4) | (f2bf(p5) << 16);
        *(unsigned int*)&pw[1 * 16 + quad * 4 + 2] = f2bf(p6) | (f2bf(p7) << 16);
        // ---- PV B-frag: 8 keys quad*8..+8 of query l15 ----
        short8 pb = *(const short8*)&Ps[wv][l15 * 40 + quad * 8];
#pragma unroll
        for (int dt = 0; dt < 4; ++dt)
          accy[dt][qt] = __builtin_amdgcn_mfma_f32_16x16x32_bf16(vf[dt], pb,
                                                                accy[dt][qt], 0, 0, 0);
      }
    }
  }

  // ---- epilogue: y^T/l -> LDS transpose (stride 72) -> coalesced stores ----
#pragma unroll
  for (int qt = 0; qt < 4; ++qt) {
    const float rl = 1.f / l_[qt];
    unsigned short* ew = &Ps[wv][l15 * 72];
#pragma unroll
    for (int dt = 0; dt < 4; ++dt) {
      const float y0 = accy[dt][qt][0] * rl;
      const float y1 = accy[dt][qt][1] * rl;
      const float y2 = accy[dt][qt][2] * rl;
      const float y3 = accy[dt][qt][3] * rl;
      *(unsigned int*)&ew[dt * 16 + quad * 4 + 0] = f2bf(y0) | (f2bf(y1) << 16);
      *(unsigned int*)&ew[dt * 16 + quad * 4 + 2] = f2bf(y2) | (f2bf(y3) << 16);
    }
    // read row l15, d-range quad*16..+16; store 2x16B (wave fills whole lines)
    const int row = wv * 64 + qt * 16 + l15;
    unsigned short* yp = Y + ((size_t)b * T_SEQ + t0 + row) * CDIM + h * 64 + quad * 16;
    uint4 v0 = *(const uint4*)&Ps[wv][l15 * 72 + quad * 16];
    uint4 v1 = *(const uint4*)&Ps[wv][l15 * 72 + quad * 16 + 8];
    *(uint4*)yp = v0;
    *(uint4*)(yp + 8) = v1;
  }
}

// ---------------------------------------------------------------------------
// ws layout (bytes): [0,96M) qkv bf16 [16384][3072]; [96M,128M) x bf16;
// [128M,160M) y bf16; [160M,166M) W_inT bf16 (permuted); [166M,168M) W_outT;
// [168M,169M) rope table float2 [4096][32]; [169M,+12K) permuted bias.
// ---------------------------------------------------------------------------
extern "C" void kernel_launch(void* const* d_in, const int* in_sizes, int n_in,
                              void* d_out, int out_size, void* d_ws, size_t ws_size,
                              hipStream_t stream) {
  const float* x     = (const float*)d_in[0];
  const float* W_in  = (const float*)d_in[1];
  const float* b_in  = (const float*)d_in[2];
  const float* W_out = (const float*)d_in[3];
  const float* b_out = (const float*)d_in[4];
  float* out = (float*)d_out;
  char* ws = (char*)d_ws;
  unsigned short* qkvb  = (unsigned short*)ws;
  unsigned short* Abf   = (unsigned short*)(ws + (96u << 20));
  unsigned short* Ybf   = (unsigned short*)(ws + (128u << 20));
  unsigned short* WinT  = (unsigned short*)(ws + (160u << 20));
  unsigned short* WoutT = (unsigned short*)(ws + (166u << 20));
  float2* ropetabp      = (float2*)(ws + (168u << 20));
  float* pbias          = (float*)(ws + (169u << 20));

  rope_tab<<<512, 256, 0, stream>>>(ropetabp);
  perm_bias<<<12, 256, 0, stream>>>(b_in, pbias);
  cvt_f32_bf16<<<8192, 256, 0, stream>>>(x, Abf);
  transpose_cvt<<<dim3(3072 / 32, 1024 / 32), 256, 0, stream>>>(W_in, WinT, 1024, 3072, 1);
  transpose_cvt<<<dim3(1024 / 32, 1024 / 32), 256, 0, stream>>>(W_out, WoutT, 1024, 1024, 0);
  gemm_bf16<<<dim3(24 * 128), 256, 0, stream>>>(
      Abf, WinT, pbias, ropetabp, qkvb, 3 * CDIM, CDIM, 1, 24);
  attn_mfma<<<dim3(T_SEQ / WIN, 16, 4), 256, 0, stream>>>(qkvb, Ybf);
  gemm_bf16<<<dim3(8 * 128), 256, 0, stream>>>(
      Ybf, WoutT, b_out, nullptr, out, CDIM, CDIM, 0, 8);
}